// Round 6
// baseline (3020.998 us; speedup 1.0000x reference)
//
#include <hip/hip_runtime.h>
#include <hip/hip_bf16.h>

#define B_  32
#define S_  4096
#define H_  1024
#define M_  (B_*S_)          // 131072 rows of enc

typedef __attribute__((ext_vector_type(8))) short bf16x8;
typedef __attribute__((ext_vector_type(4))) float f32x4;
typedef __attribute__((ext_vector_type(8))) unsigned short ushort8;

typedef void __attribute__((address_space(3)))* lds_ptr_t;
typedef void __attribute__((address_space(1)))* gbl_ptr_t;

__device__ __forceinline__ unsigned short f2bf(float x) {
    return __builtin_bit_cast(unsigned short, __float2bfloat16(x));
}
__device__ __forceinline__ float bf2f(unsigned short u) {
    return __builtin_bit_cast(float, (unsigned)u << 16);
}
__device__ __forceinline__ float tanh_fast(float x) {
    float e = __expf(2.0f * x);
    return 1.0f - 2.0f / (e + 1.0f);
}

// ---------------- fp32 -> bf16 converters ----------------
__global__ __launch_bounds__(256) void k_cvt_bf16(const float* __restrict__ in,
                                                  unsigned short* __restrict__ out, int n4) {
    int i = blockIdx.x * 256 + threadIdx.x;
    if (i < n4) {
        float4 f = reinterpret_cast<const float4*>(in)[i];
        ushort4 u;
        u.x = f2bf(f.x); u.y = f2bf(f.y); u.z = f2bf(f.z); u.w = f2bf(f.w);
        reinterpret_cast<ushort4*>(out)[i] = u;
    }
}

__global__ __launch_bounds__(256) void k_cvt_enc(const float* __restrict__ in,
                                                 unsigned short* __restrict__ out, int n8) {
    const int stride = gridDim.x * 256;
    for (int i = blockIdx.x * 256 + threadIdx.x; i < n8; i += stride) {
        float4 a = reinterpret_cast<const float4*>(in)[(size_t)i * 2];
        float4 b = reinterpret_cast<const float4*>(in)[(size_t)i * 2 + 1];
        ushort8 u;
        u[0] = f2bf(a.x); u[1] = f2bf(a.y); u[2] = f2bf(a.z); u[3] = f2bf(a.w);
        u[4] = f2bf(b.x); u[5] = f2bf(b.y); u[6] = f2bf(b.z); u[7] = f2bf(b.w);
        reinterpret_cast<ushort8*>(out)[i] = u;
    }
}

// ---------------- q_proj[b][o] = sum_k query[b][k] * Ws[o][k] ----------------
__global__ __launch_bounds__(256) void k_qproj(const float* __restrict__ q,
                                               const float* __restrict__ Ws,
                                               float* __restrict__ qp) {
    const int b = blockIdx.y, oc = blockIdx.x, tid = threadIdx.x;
    __shared__ float ql[H_];
    for (int i = tid; i < H_; i += 256) ql[i] = q[b*H_ + i];
    __syncthreads();
    const int o = oc*256 + tid;
    const float4* w = reinterpret_cast<const float4*>(&Ws[(size_t)o * H_]);
    float acc = 0.f;
    #pragma unroll 4
    for (int k4 = 0; k4 < H_/4; ++k4) {
        float4 ww = w[k4];
        acc += ql[k4*4+0]*ww.x + ql[k4*4+1]*ww.y + ql[k4*4+2]*ww.z + ql[k4*4+3]*ww.w;
    }
    qp[b*H_ + o] = acc;
}

// ---------------- fused scores GEMM: 256x256 tile, BK=32, 2 blocks/CU ----------------
// LDS 64 KiB (2 bufs x (A 16K + B 16K)), 1024B subtiles in MFMA fragment order
// (conflict-free ds_read_b128 at subtile_base + lane*16; staged via per-lane
// pre-permuted global source, linear LDS dest). 2 phases per K-tile (mq halves),
// B held in regs across both phases. vmcnt(4) ledger at every phase end.
__global__ __launch_bounds__(512, 4) void k_scores8(const unsigned short* __restrict__ encb,
                                                    const unsigned short* __restrict__ whb,
                                                    const float* __restrict__ qp,
                                                    const float* __restrict__ vw,
                                                    float* __restrict__ sp) {
    __shared__ __align__(1024) char smem[65536];

    const int tid = threadIdx.x;
    const int l   = tid & 63;
    const int w   = tid >> 6;      // wave 0..7
    const int wr  = w >> 2;        // 0..1  (row half: mblks wr*8..+7)
    const int wc  = w & 3;         // 0..3  (col quarter: nblks wc*4..+3)
    const int fr  = l & 15;
    const int fh  = l >> 4;

    // XCD-group swizzle: 4 bn tiles of one bm adjacent on the same XCD
    const int hb = blockIdx.x;                // 2048 blocks, 2048 % 8 == 0
    const int L  = (hb & 7) * 256 + (hb >> 3);
    const int bm = L >> 2;
    const int bn = L & 3;
    const int row0 = bm * 256;
    const int col0 = bn * 256;
    const int b = row0 >> 12;

    // ---- staging descriptors (invariant; fragment-order source lane-map) ----
    // A region r (r = phase that READS it): mblk = (w&3) + r*4 + (w>>2)*8
    const unsigned short* srcA[2]; int dstA[2];
    #pragma unroll
    for (int r = 0; r < 2; ++r) {
        const int mblk = (w & 3) + r*4 + ((w >> 2) << 3);
        srcA[r] = encb + (size_t)(row0 + mblk*16 + fr) * H_ + fh*8;
        dstA[r] = mblk*1024 + l*16;
    }
    const unsigned short* srcB[2]; int dstB[2];
    #pragma unroll
    for (int j = 0; j < 2; ++j) {
        const int nblk = j*8 + w;
        srcB[j] = whb + (size_t)(col0 + nblk*16 + fr) * H_ + fh*8;
        dstB[j] = 16384 + nblk*1024 + l*16;
    }

    auto stA = [&](int t, int r) {
        __builtin_amdgcn_global_load_lds((gbl_ptr_t)(srcA[r] + t*32),
            (lds_ptr_t)(smem + ((t & 1) << 15) + dstA[r]), 16, 0, 0);
    };
    auto stB = [&](int t) {
        #pragma unroll
        for (int j = 0; j < 2; ++j)
            __builtin_amdgcn_global_load_lds((gbl_ptr_t)(srcB[j] + t*32),
                (lds_ptr_t)(smem + ((t & 1) << 15) + dstB[j]), 16, 0, 0);
    };

    const int aBase = wr*8192 + l*16;           // + (mq*4+m2)*1024 + (buf<<15)
    const int bBase = 16384 + wc*4096 + l*16;   // + n2*1024 + (buf<<15)

    f32x4  acc[8][4] = {};
    bf16x8 af[4];   // current mq's A fragments
    bf16x8 ba[4];   // K-tile's B fragments (held across both phases)

    auto ldA = [&](int buf, int mq) {
        #pragma unroll
        for (int m2 = 0; m2 < 4; ++m2)
            af[m2] = *reinterpret_cast<const bf16x8*>(
                smem + (buf << 15) + aBase + (mq*4 + m2)*1024);
    };
    auto ldB = [&](int buf) {
        #pragma unroll
        for (int n2 = 0; n2 < 4; ++n2)
            ba[n2] = *reinterpret_cast<const bf16x8*>(
                smem + (buf << 15) + bBase + n2*1024);
    };
    auto mfma16 = [&](int mq) {
        __builtin_amdgcn_s_setprio(1);
        #pragma unroll
        for (int m2 = 0; m2 < 4; ++m2)
            #pragma unroll
            for (int n2 = 0; n2 < 4; ++n2)
                acc[mq*4+m2][n2] = __builtin_amdgcn_mfma_f32_16x16x32_bf16(
                    af[m2], ba[n2], acc[mq*4+m2][n2], 0, 0, 0);
        __builtin_amdgcn_s_setprio(0);
    };
    auto barrier = [] { asm volatile("s_barrier" ::: "memory"); };

    // prologue: t0 fully + t1 {A-r0, B}; vmcnt(3) forces t0 complete
    stA(0, 0); stA(0, 1); stB(0);
    stA(1, 0); stB(1);
    asm volatile("s_waitcnt vmcnt(3)" ::: "memory");
    barrier();

    // ledger (per wave, 4 issues/tile): at t.ph1-end vmcnt(4) drains A(t,r1);
    // at t.ph2-end vmcnt(4) drains {A(t+1,r0), B(t+1)x2}. Cross-wave safety:
    // each wave's MFMAs consume its ds_reads BEFORE its barrier arrival, so a
    // post-barrier stage never overwrites an un-read subtile.
    #pragma unroll
    for (int t = 0; t < 32; ++t) {
        const int buf = t & 1;
        // phase 1: mq0 (reads A m0..3 + all B; stage next tile's A-r1)
        ldA(buf, 0); ldB(buf);
        if (t <= 30) stA(t+1, 1);
        mfma16(0);
        if (t <= 30) asm volatile("s_waitcnt vmcnt(4)" ::: "memory");
        else         asm volatile("s_waitcnt vmcnt(0)" ::: "memory");
        barrier();
        // phase 2: mq1 (reads A m4..7; stage tile t+2's A-r0 + B)
        ldA(buf, 1);
        if (t <= 29) { stA(t+2, 0); stB(t+2); }
        mfma16(1);
        if (t <= 29)      asm volatile("s_waitcnt vmcnt(4)" ::: "memory");
        else if (t == 30) asm volatile("s_waitcnt vmcnt(1)" ::: "memory");
        barrier();
    }

    // ---- epilogue: s_partial[row] = sum_c v[c] * tanh(qp[b][c] + x[row][c]) ----
    float vv[4], qq[4];
    #pragma unroll
    for (int n = 0; n < 4; ++n) {
        int c = col0 + wc*64 + n*16 + fr;
        vv[n] = vw[c];
        qq[n] = qp[b*H_ + c];
    }
    float* sred = (float*)smem;   // aliases buf0 (idle; all waves past final barrier)
    #pragma unroll
    for (int m = 0; m < 8; ++m)
        #pragma unroll
        for (int r = 0; r < 4; ++r) {
            float s = 0.f;
            #pragma unroll
            for (int n = 0; n < 4; ++n)
                s += vv[n] * tanh_fast(qq[n] + acc[m][n][r]);
            s += __shfl_xor(s, 1, 64); s += __shfl_xor(s, 2, 64);
            s += __shfl_xor(s, 4, 64); s += __shfl_xor(s, 8, 64);
            if (fr == 0) sred[wc*256 + wr*128 + m*16 + fh*4 + r] = s;
        }
    __syncthreads();
    if (tid < 256) {
        float s = sred[tid] + sred[256 + tid] + sred[512 + tid] + sred[768 + tid];
        sp[(size_t)bn * M_ + row0 + tid] = s;
    }
}

// ---------------- fused scores GEMM, fp32 A in-flight (fallback, 128^2) ----------------
__global__ __launch_bounds__(256) void k_scores_f(const float* __restrict__ enc,
                                                  const unsigned short* __restrict__ whb,
                                                  const float* __restrict__ qp,
                                                  const float* __restrict__ vw,
                                                  float* __restrict__ sp) {
    __shared__ __align__(16) unsigned short As[2][128][32];
    __shared__ __align__(16) unsigned short Bs[2][128][32];
    __shared__ float sred[2][128];

    const int tid  = threadIdx.x;
    const int lane = tid & 63;
    const int wid  = tid >> 6;
    const int wr = wid >> 1, wc = wid & 1;
    const int fr = lane & 15;
    const int fk = (lane >> 4) * 8;

    const int h  = blockIdx.x;
    const int L  = (h & 7) * 1024 + (h >> 3);
    const int bm = L >> 3;
    const int bn = L & 7;
    const int row0 = bm * 128;
    const int col0 = bn * 128;
    const int b = row0 >> 12;

    const int ar = tid >> 3;
    const int ak = (tid & 7) * 4;
    const int bnr = tid >> 2;
    const int bkk = (tid & 3) * 8;

    float4 areg[4];
    auto loadA = [&](int kt) {
        #pragma unroll
        for (int p = 0; p < 4; ++p)
            areg[p] = *reinterpret_cast<const float4*>(
                &enc[(size_t)(row0 + p*32 + ar) * H_ + kt*32 + ak]);
    };
    auto writeA = [&](int buf) {
        #pragma unroll
        for (int p = 0; p < 4; ++p) {
            ushort4 u;
            u.x = f2bf(areg[p].x); u.y = f2bf(areg[p].y);
            u.z = f2bf(areg[p].z); u.w = f2bf(areg[p].w);
            *reinterpret_cast<ushort4*>(&As[buf][p*32 + ar][ak]) = u;
        }
    };
    auto stageB = [&](int buf, int kt) {
        const unsigned short* g0 = whb + (size_t)(col0 + bnr) * H_ + kt*32 + bkk;
        const unsigned short* g1 = g0 + (size_t)64 * H_;
        char* l0 = (char*)(&Bs[buf][0][0]) + tid*16;
        __builtin_amdgcn_global_load_lds((gbl_ptr_t)g0, (lds_ptr_t)l0,        16, 0, 0);
        __builtin_amdgcn_global_load_lds((gbl_ptr_t)g1, (lds_ptr_t)(l0+4096), 16, 0, 0);
    };

    f32x4 acc[4][4] = {};

    loadA(0);
    stageB(0, 0);
    writeA(0);
    __syncthreads();

    for (int kt = 0; kt < 32; ++kt) {
        const int cur = kt & 1, nxt = cur ^ 1;
        if (kt < 31) { stageB(nxt, kt + 1); loadA(kt + 1); }

        bf16x8 af[4], bfr[4];
        #pragma unroll
        for (int i = 0; i < 4; ++i) {
            af[i]  = *reinterpret_cast<const bf16x8*>(&As[cur][wr*64 + i*16 + fr][fk]);
            bfr[i] = *reinterpret_cast<const bf16x8*>(&Bs[cur][wc*64 + i*16 + fr][fk]);
        }
        #pragma unroll
        for (int i = 0; i < 4; ++i)
            #pragma unroll
            for (int j = 0; j < 4; ++j)
                acc[i][j] = __builtin_amdgcn_mfma_f32_16x16x32_bf16(af[i], bfr[j], acc[i][j], 0, 0, 0);

        if (kt < 31) writeA(nxt);
        __syncthreads();
    }

    float vv[4], qq[4];
    #pragma unroll
    for (int j = 0; j < 4; ++j) {
        int c = col0 + wc*64 + j*16 + fr;
        vv[j] = vw[c];
        qq[j] = qp[b*H_ + c];
    }
    #pragma unroll
    for (int i = 0; i < 4; ++i) {
        #pragma unroll
        for (int r = 0; r < 4; ++r) {
            float s = 0.f;
            #pragma unroll
            for (int j = 0; j < 4; ++j)
                s += vv[j] * tanh_fast(qq[j] + acc[i][j][r]);
            #pragma unroll
            for (int m = 1; m < 16; m <<= 1)
                s += __shfl_xor(s, m, 64);
            if (fr == 0)
                sred[wc][wr*64 + i*16 + (lane >> 4)*4 + r] = s;
        }
    }
    __syncthreads();
    if (tid < 128)
        sp[(size_t)bn * M_ + row0 + tid] = sred[0][tid] + sred[1][tid];
}

// ---------------- softmax over S per batch (P partial panels) ----------------
__global__ __launch_bounds__(256) void k_softmax(const float* __restrict__ sp,
                                                 float* __restrict__ attn, int P) {
    const int b = blockIdx.x, tid = threadIdx.x;
    __shared__ float red[4];
    float vals[16];
    float mx = -1e30f;
    #pragma unroll
    for (int i = 0; i < 16; ++i) {
        int s = i*256 + tid;
        float x = 0.f;
        for (int p = 0; p < P; ++p) x += sp[(size_t)p*M_ + b*S_ + s];
        vals[i] = x;
        mx = fmaxf(mx, x);
    }
    #pragma unroll
    for (int m = 1; m < 64; m <<= 1) mx = fmaxf(mx, __shfl_xor(mx, m, 64));
    if ((tid & 63) == 0) red[tid >> 6] = mx;
    __syncthreads();
    mx = fmaxf(fmaxf(red[0], red[1]), fmaxf(red[2], red[3]));
    float sum = 0.f;
    #pragma unroll
    for (int i = 0; i < 16; ++i) { vals[i] = __expf(vals[i] - mx); sum += vals[i]; }
    #pragma unroll
    for (int m = 1; m < 64; m <<= 1) sum += __shfl_xor(sum, m, 64);
    __syncthreads();
    if ((tid & 63) == 0) red[tid >> 6] = sum;
    __syncthreads();
    sum = red[0] + red[1] + red[2] + red[3];
    float inv = 1.f / sum;
    #pragma unroll
    for (int i = 0; i < 16; ++i) attn[b*S_ + i*256 + tid] = vals[i] * inv;
}

// ---------------- ctx partials, bf16 enc ----------------
__global__ __launch_bounds__(256) void k_ctx_b(const float* __restrict__ attn,
                                               const unsigned short* __restrict__ encb,
                                               float* __restrict__ ctxp) {
    const int sc = blockIdx.x;      // 0..15
    const int b  = blockIdx.y;
    const int hh = threadIdx.x * 4;
    float ax = 0.f, ay = 0.f, az = 0.f, aw = 0.f;
    const int s0 = sc * 256;
    #pragma unroll 4
    for (int s = s0; s < s0 + 256; ++s) {
        float a = attn[b*S_ + s];
        ushort4 e = *reinterpret_cast<const ushort4*>(&encb[((size_t)b*S_ + s) * H_ + hh]);
        ax += a*bf2f(e.x); ay += a*bf2f(e.y); az += a*bf2f(e.z); aw += a*bf2f(e.w);
    }
    float4 o; o.x = ax; o.y = ay; o.z = az; o.w = aw;
    *reinterpret_cast<float4*>(&ctxp[((size_t)sc*B_ + b) * H_ + hh]) = o;
}

// ---------------- ctx partials, fp32 enc (fallback) ----------------
__global__ __launch_bounds__(256) void k_ctx_f(const float* __restrict__ attn,
                                               const float* __restrict__ enc,
                                               float* __restrict__ ctxp) {
    const int sc = blockIdx.x;
    const int b  = blockIdx.y;
    const int hh = threadIdx.x * 4;
    float ax = 0.f, ay = 0.f, az = 0.f, aw = 0.f;
    const int s0 = sc * 256;
    #pragma unroll 4
    for (int s = s0; s < s0 + 256; ++s) {
        float a = attn[b*S_ + s];
        float4 e = *reinterpret_cast<const float4*>(&enc[((size_t)b*S_ + s) * H_ + hh]);
        ax += a*e.x; ay += a*e.y; az += a*e.z; aw += a*e.w;
    }
    float4 o; o.x = ax; o.y = ay; o.z = az; o.w = aw;
    *reinterpret_cast<float4*>(&ctxp[((size_t)sc*B_ + b) * H_ + hh]) = o;
}

// ---------------- out[b][o] = tanh(sum_k cat[b][k] * Wout[o][k]) ----------------
__global__ __launch_bounds__(256) void k_out(const float* __restrict__ ctxp,
                                             const float* __restrict__ q,
                                             const float* __restrict__ Wout,
                                             float* __restrict__ out) {
    const int oc = blockIdx.x, b = blockIdx.y, tid = threadIdx.x;
    __shared__ float cat[2*H_];
    for (int k = tid; k < H_; k += 256) {
        float s = 0.f;
        #pragma unroll
        for (int p = 0; p < 16; ++p) s += ctxp[((size_t)p*B_ + b) * H_ + k];
        cat[k] = s;
        cat[H_ + k] = q[b*H_ + k];
    }
    __syncthreads();
    const int o = oc*256 + tid;
    const float4* w = reinterpret_cast<const float4*>(&Wout[(size_t)o * 2*H_]);
    float acc = 0.f;
    #pragma unroll 4
    for (int k4 = 0; k4 < 2*H_/4; ++k4) {
        float4 ww = w[k4];
        acc += cat[k4*4+0]*ww.x + cat[k4*4+1]*ww.y + cat[k4*4+2]*ww.z + cat[k4*4+3]*ww.w;
    }
    out[b*H_ + o] = tanh_fast(acc);
}

extern "C" void kernel_launch(void* const* d_in, const int* in_sizes, int n_in,
                              void* d_out, int out_size, void* d_ws, size_t ws_size,
                              hipStream_t stream) {
    const float* query = (const float*)d_in[0];
    const float* enc   = (const float*)d_in[1];
    // d_in[2] = src_lengths (int64) — dead in the reference, faithfully unused
    const float* Ws    = (const float*)d_in[3];
    const float* Wh    = (const float*)d_in[4];
    const float* vw    = (const float*)d_in[5];
    const float* Wout  = (const float*)d_in[6];
    float* out = (float*)d_out;

    char* ws = (char*)d_ws;

    if (ws_size >= (266ull << 20)) {
        unsigned short* encb = (unsigned short*)ws;                        // 256 MiB
        unsigned short* whb  = (unsigned short*)(ws + (256ull << 20));     // 2 MiB
        float* sp   = (float*)(ws + (258ull << 20));                       // [4][M] 2 MiB
        float* attn = (float*)(ws + (262ull << 20));                       // 512 KiB
        float* qp   = (float*)(ws + (262ull << 20) + (512u << 10));        // 128 KiB
        float* ctxp = (float*)(ws + (263ull << 20));                       // 2 MiB

        k_cvt_enc <<<dim3(2048),    dim3(256), 0, stream>>>(enc, encb, M_*H_/8);
        k_cvt_bf16<<<dim3(1024),    dim3(256), 0, stream>>>(Wh, whb, H_*H_/4);
        k_qproj   <<<dim3(4, 32),   dim3(256), 0, stream>>>(query, Ws, qp);
        k_scores8 <<<dim3(2048),    dim3(512), 0, stream>>>(encb, whb, qp, vw, sp);
        k_softmax <<<dim3(32),      dim3(256), 0, stream>>>(sp, attn, 4);
        k_ctx_b   <<<dim3(16, 32),  dim3(256), 0, stream>>>(attn, encb, ctxp);
        k_out     <<<dim3(4, 32),   dim3(256), 0, stream>>>(ctxp, query, Wout, out);
    } else {
        unsigned short* whb = (unsigned short*)ws;
        float* sp   = (float*)(ws + (2u  << 20));
        float* attn = (float*)(ws + (6u  << 20));
        float* qp   = (float*)(ws + (6u  << 20) + (512u << 10));
        float* ctxp = (float*)(ws + (7u  << 20));

        k_cvt_bf16<<<dim3(1024),    dim3(256), 0, stream>>>(Wh, whb, H_*H_/4);
        k_qproj   <<<dim3(4, 32),   dim3(256), 0, stream>>>(query, Ws, qp);
        k_scores_f<<<dim3(8192),    dim3(256), 0, stream>>>(enc, whb, qp, vw, sp);
        k_softmax <<<dim3(32),      dim3(256), 0, stream>>>(sp, attn, 8);
        k_ctx_f   <<<dim3(16, 32),  dim3(256), 0, stream>>>(attn, enc, ctxp);
        k_out     <<<dim3(4, 32),   dim3(256), 0, stream>>>(ctxp, query, Wout, out);
    }
}

// Round 7
// 974.277 us; speedup vs baseline: 3.1008x; 3.1008x over previous
//
#include <hip/hip_runtime.h>
#include <hip/hip_bf16.h>

#define B_  32
#define S_  4096
#define H_  1024
#define M_  (B_*S_)          // 131072 rows of enc

typedef __attribute__((ext_vector_type(8))) short bf16x8;
typedef __attribute__((ext_vector_type(4))) float f32x4;
typedef __attribute__((ext_vector_type(8))) unsigned short ushort8;

typedef void __attribute__((address_space(3)))* lds_ptr_t;
typedef void __attribute__((address_space(1)))* gbl_ptr_t;

__device__ __forceinline__ unsigned short f2bf(float x) {
    return __builtin_bit_cast(unsigned short, __float2bfloat16(x));
}
__device__ __forceinline__ float tanh_fast(float x) {
    float e = __expf(2.0f * x);
    return 1.0f - 2.0f / (e + 1.0f);
}

// ---------------- Wh fp32 -> bf16 (2 MB, one-time per call) ----------------
__global__ __launch_bounds__(256) void k_cvt_bf16(const float* __restrict__ in,
                                                  unsigned short* __restrict__ out, int n4) {
    int i = blockIdx.x * 256 + threadIdx.x;
    if (i < n4) {
        float4 f = reinterpret_cast<const float4*>(in)[i];
        ushort4 u;
        u.x = f2bf(f.x); u.y = f2bf(f.y); u.z = f2bf(f.z); u.w = f2bf(f.w);
        reinterpret_cast<ushort4*>(out)[i] = u;
    }
}

// ---------------- q_proj[b][o] = sum_k query[b][k] * Ws[o][k] ----------------
__global__ __launch_bounds__(256) void k_qproj(const float* __restrict__ q,
                                               const float* __restrict__ Ws,
                                               float* __restrict__ qp) {
    const int b = blockIdx.y, oc = blockIdx.x, tid = threadIdx.x;
    __shared__ float ql[H_];
    for (int i = tid; i < H_; i += 256) ql[i] = q[b*H_ + i];
    __syncthreads();
    const int o = oc*256 + tid;
    const float4* w = reinterpret_cast<const float4*>(&Ws[(size_t)o * H_]);
    float acc = 0.f;
    #pragma unroll 4
    for (int k4 = 0; k4 < H_/4; ++k4) {
        float4 ww = w[k4];
        acc += ql[k4*4+0]*ww.x + ql[k4*4+1]*ww.y + ql[k4*4+2]*ww.z + ql[k4*4+3]*ww.w;
    }
    qp[b*H_ + o] = acc;
}

// ---------------- fused scores GEMM: 128x128 tile, fused fp32->bf16 A-staging ----------------
// 4 waves (2x2), wave tile 64x64 (acc 64 VGPR) -> ~3 blocks/CU co-resident.
// A: global fp32 -> reg (depth-2 ping-pong) -> cvt -> ds_write, fragment-order subtiles.
// B: whb bf16 via global_load_lds, fragment-order, triple-buffered.
// Counted vmcnt(6) per tile: drains exactly {A(t+1) 4 loads, B(t+1) 2 loads}.
// LDS 40KB: A 2x8KB @0, B 3x8KB @16384. Conflict-free ds_read_b128 (base + lane*16).
__global__ __launch_bounds__(256, 3) void k_scores_r(const float* __restrict__ enc,
                                                     const unsigned short* __restrict__ whb,
                                                     const float* __restrict__ qp,
                                                     const float* __restrict__ vw,
                                                     float* __restrict__ sp) {
    __shared__ __align__(1024) char smem[40960];

    const int tid = threadIdx.x;
    const int l   = tid & 63;
    const int w   = tid >> 6;      // wave 0..3
    const int wr  = w >> 1;        // 0..1 (row half: rows wr*64..+63)
    const int wc  = w & 1;         // 0..1 (col half: cols wc*64..+63)
    const int fr  = l & 15;
    const int fh  = l >> 4;

    // XCD-group swizzle: the 8 bn tiles of one bm adjacent on the same XCD
    const int hb = blockIdx.x;                 // 8192 blocks, 8192 % 8 == 0
    const int L  = (hb & 7) * 1024 + (hb >> 3);
    const int bm = L >> 3;
    const int bn = L & 7;
    const int row0 = bm * 128;
    const int col0 = bn * 128;
    const int b = row0 >> 12;

    // ---- invariant source bases (fragment-order lane map: row fr, k-chunk fh*8) ----
    const float* srcA[2];          // A subtiles rblk = {w, 4+w}
    #pragma unroll
    for (int sub = 0; sub < 2; ++sub) {
        const int rblk = sub*4 + w;
        srcA[sub] = enc + (size_t)(row0 + rblk*16 + fr) * H_ + fh*8;
    }
    const unsigned short* srcB[2]; // B subtiles nblk = {w, 4+w}
    #pragma unroll
    for (int j = 0; j < 2; ++j) {
        const int nblk = j*4 + w;
        srcB[j] = whb + (size_t)(col0 + nblk*16 + fr) * H_ + fh*8;
    }

    float4 fset[2][2][2];          // [set][sub][half] fp32 staging, static idx under unroll

    auto loadA = [&](int t, int set) {        // 4 global_load_dwordx4 (imm offset t*128B)
        #pragma unroll
        for (int sub = 0; sub < 2; ++sub) {
            fset[set][sub][0] = *reinterpret_cast<const float4*>(srcA[sub] + t*32);
            fset[set][sub][1] = *reinterpret_cast<const float4*>(srcA[sub] + t*32 + 4);
        }
    };
    auto stageB = [&](int t) {                // 2 global_load_lds -> buf t%3
        #pragma unroll
        for (int j = 0; j < 2; ++j)
            __builtin_amdgcn_global_load_lds((gbl_ptr_t)(srcB[j] + t*32),
                (lds_ptr_t)(smem + 16384 + (t % 3)*8192 + (j*4 + w)*1024 + l*16), 16, 0, 0);
    };
    auto cvtWrite = [&](int set, int buf) {   // fp32 set -> bf16 -> 2 ds_write_b128
        #pragma unroll
        for (int sub = 0; sub < 2; ++sub) {
            ushort8 u;
            #pragma unroll
            for (int hlf = 0; hlf < 2; ++hlf) {
                float4 f = fset[set][sub][hlf];
                u[hlf*4+0] = f2bf(f.x); u[hlf*4+1] = f2bf(f.y);
                u[hlf*4+2] = f2bf(f.z); u[hlf*4+3] = f2bf(f.w);
            }
            *reinterpret_cast<ushort8*>(smem + buf*8192 + (sub*4 + w)*1024 + l*16) = u;
        }
    };

    f32x4  acc[4][4] = {};
    bf16x8 af[4], ba[4];

    auto ldFrags = [&](int t) {
        #pragma unroll
        for (int m2 = 0; m2 < 4; ++m2)
            af[m2] = *reinterpret_cast<const bf16x8*>(
                smem + (t & 1)*8192 + (wr*4 + m2)*1024 + l*16);
        #pragma unroll
        for (int n2 = 0; n2 < 4; ++n2)
            ba[n2] = *reinterpret_cast<const bf16x8*>(
                smem + 16384 + (t % 3)*8192 + (wc*4 + n2)*1024 + l*16);
    };
    auto mfma16 = [&] {
        __builtin_amdgcn_s_setprio(1);
        #pragma unroll
        for (int m2 = 0; m2 < 4; ++m2)
            #pragma unroll
            for (int n2 = 0; n2 < 4; ++n2)
                acc[m2][n2] = __builtin_amdgcn_mfma_f32_16x16x32_bf16(
                    af[m2], ba[n2], acc[m2][n2], 0, 0, 0);
        __builtin_amdgcn_s_setprio(0);
    };
    auto barrier = [] { asm volatile("s_barrier" ::: "memory"); };

    // ---- prologue: A(0),B(0),A(1),B(1) in flight; drain A0,B0,A1 ----
    loadA(0, 0); stageB(0); loadA(1, 1); stageB(1);
    asm volatile("s_waitcnt vmcnt(2)" ::: "memory");
    cvtWrite(0, 0);
    asm volatile("s_waitcnt lgkmcnt(0)" ::: "memory");
    barrier();

    // ---- main loop: per tile t, queue = [A(t+1),B(t+1),A(t+2),B(t+2)];
    //      vmcnt(6) drains exactly A(t+1),B(t+1); convert AFTER the drain. ----
    #pragma unroll
    for (int t = 0; t < 32; ++t) {
        ldFrags(t);
        if (t <= 29) { loadA(t+2, t & 1); stageB(t+2); }
        mfma16();
        if (t <= 29)      asm volatile("s_waitcnt vmcnt(6)" ::: "memory");
        else if (t == 30) asm volatile("s_waitcnt vmcnt(0)" ::: "memory");
        if (t <= 30) {
            cvtWrite((t+1) & 1, (t+1) & 1);
            asm volatile("s_waitcnt lgkmcnt(0)" ::: "memory");
        }
        if (t <= 30) barrier();
    }
    __syncthreads();

    // ---- epilogue: s_partial[row] = sum_c v[c] * tanh(qp[b][c] + x[row][c]) ----
    float vv[4], qq[4];
    #pragma unroll
    for (int n = 0; n < 4; ++n) {
        int c = col0 + wc*64 + n*16 + fr;
        vv[n] = vw[c];
        qq[n] = qp[b*H_ + c];
    }
    float* sred = (float*)smem;   // 1KB, aliases A buf0 (idle)
    #pragma unroll
    for (int m2 = 0; m2 < 4; ++m2)
        #pragma unroll
        for (int r = 0; r < 4; ++r) {
            float s = 0.f;
            #pragma unroll
            for (int n = 0; n < 4; ++n)
                s += vv[n] * tanh_fast(qq[n] + acc[m2][n][r]);
            s += __shfl_xor(s, 1, 64); s += __shfl_xor(s, 2, 64);
            s += __shfl_xor(s, 4, 64); s += __shfl_xor(s, 8, 64);
            if (fr == 0) sred[wc*128 + wr*64 + m2*16 + fh*4 + r] = s;
        }
    __syncthreads();
    if (tid < 128)
        sp[(size_t)bn * M_ + row0 + tid] = sred[tid] + sred[128 + tid];
}

// ---------------- softmax over S per batch (P partial panels) ----------------
__global__ __launch_bounds__(256) void k_softmax(const float* __restrict__ sp,
                                                 float* __restrict__ attn, int P) {
    const int b = blockIdx.x, tid = threadIdx.x;
    __shared__ float red[4];
    float vals[16];
    float mx = -1e30f;
    #pragma unroll
    for (int i = 0; i < 16; ++i) {
        int s = i*256 + tid;
        float x = 0.f;
        for (int p = 0; p < P; ++p) x += sp[(size_t)p*M_ + b*S_ + s];
        vals[i] = x;
        mx = fmaxf(mx, x);
    }
    #pragma unroll
    for (int m = 1; m < 64; m <<= 1) mx = fmaxf(mx, __shfl_xor(mx, m, 64));
    if ((tid & 63) == 0) red[tid >> 6] = mx;
    __syncthreads();
    mx = fmaxf(fmaxf(red[0], red[1]), fmaxf(red[2], red[3]));
    float sum = 0.f;
    #pragma unroll
    for (int i = 0; i < 16; ++i) { vals[i] = __expf(vals[i] - mx); sum += vals[i]; }
    #pragma unroll
    for (int m = 1; m < 64; m <<= 1) sum += __shfl_xor(sum, m, 64);
    __syncthreads();
    if ((tid & 63) == 0) red[tid >> 6] = sum;
    __syncthreads();
    sum = red[0] + red[1] + red[2] + red[3];
    float inv = 1.f / sum;
    #pragma unroll
    for (int i = 0; i < 16; ++i) attn[b*S_ + i*256 + tid] = vals[i] * inv;
}

// ---------------- ctx partials, fp32 enc ----------------
__global__ __launch_bounds__(256) void k_ctx_f(const float* __restrict__ attn,
                                               const float* __restrict__ enc,
                                               float* __restrict__ ctxp) {
    const int sc = blockIdx.x;      // 0..15
    const int b  = blockIdx.y;
    const int hh = threadIdx.x * 4;
    float ax = 0.f, ay = 0.f, az = 0.f, aw = 0.f;
    const int s0 = sc * 256;
    #pragma unroll 4
    for (int s = s0; s < s0 + 256; ++s) {
        float a = attn[b*S_ + s];
        float4 e = *reinterpret_cast<const float4*>(&enc[((size_t)b*S_ + s) * H_ + hh]);
        ax += a*e.x; ay += a*e.y; az += a*e.z; aw += a*e.w;
    }
    float4 o; o.x = ax; o.y = ay; o.z = az; o.w = aw;
    *reinterpret_cast<float4*>(&ctxp[((size_t)sc*B_ + b) * H_ + hh]) = o;
}

// ---------------- out[b][o] = tanh(sum_k cat[b][k] * Wout[o][k]) ----------------
__global__ __launch_bounds__(256) void k_out(const float* __restrict__ ctxp,
                                             const float* __restrict__ q,
                                             const float* __restrict__ Wout,
                                             float* __restrict__ out) {
    const int oc = blockIdx.x, b = blockIdx.y, tid = threadIdx.x;
    __shared__ float cat[2*H_];
    for (int k = tid; k < H_; k += 256) {
        float s = 0.f;
        #pragma unroll
        for (int p = 0; p < 16; ++p) s += ctxp[((size_t)p*B_ + b) * H_ + k];
        cat[k] = s;
        cat[H_ + k] = q[b*H_ + k];
    }
    __syncthreads();
    const int o = oc*256 + tid;
    const float4* w = reinterpret_cast<const float4*>(&Wout[(size_t)o * 2*H_]);
    float acc = 0.f;
    #pragma unroll 4
    for (int k4 = 0; k4 < 2*H_/4; ++k4) {
        float4 ww = w[k4];
        acc += cat[k4*4+0]*ww.x + cat[k4*4+1]*ww.y + cat[k4*4+2]*ww.z + cat[k4*4+3]*ww.w;
    }
    out[b*H_ + o] = tanh_fast(acc);
}

extern "C" void kernel_launch(void* const* d_in, const int* in_sizes, int n_in,
                              void* d_out, int out_size, void* d_ws, size_t ws_size,
                              hipStream_t stream) {
    const float* query = (const float*)d_in[0];
    const float* enc   = (const float*)d_in[1];
    // d_in[2] = src_lengths (int64) — dead in the reference, faithfully unused
    const float* Ws    = (const float*)d_in[3];
    const float* Wh    = (const float*)d_in[4];
    const float* vw    = (const float*)d_in[5];
    const float* Wout  = (const float*)d_in[6];
    float* out = (float*)d_out;

    char* ws = (char*)d_ws;
    unsigned short* whb = (unsigned short*)ws;                 // [1024][1024] bf16, 2 MiB
    float* sp   = (float*)(ws + (2u  << 20));                  // [8][M] 4 MiB
    float* attn = (float*)(ws + (6u  << 20));                  // 512 KiB
    float* qp   = (float*)(ws + (6u  << 20) + (512u << 10));   // 128 KiB
    float* ctxp = (float*)(ws + (7u  << 20));                  // [16][32][1024] 2 MiB
    // total ws footprint: 9 MiB; every buffer fully written before read each call

    k_cvt_bf16<<<dim3(1024),   dim3(256), 0, stream>>>(Wh, whb, H_*H_/4);
    k_qproj   <<<dim3(4, 32),  dim3(256), 0, stream>>>(query, Ws, qp);
    k_scores_r<<<dim3(8192),   dim3(256), 0, stream>>>(enc, whb, qp, vw, sp);
    k_softmax <<<dim3(32),     dim3(256), 0, stream>>>(sp, attn, 8);
    k_ctx_f   <<<dim3(16, 32), dim3(256), 0, stream>>>(attn, enc, ctxp);
    k_out     <<<dim3(4, 32),  dim3(256), 0, stream>>>(ctxp, query, Wout, out);
}

// Round 8
// 827.777 us; speedup vs baseline: 3.6495x; 1.1770x over previous
//
#include <hip/hip_runtime.h>
#include <hip/hip_bf16.h>

#define B_  32
#define S_  4096
#define H_  1024
#define M_  (B_*S_)          // 131072 rows of enc

typedef __attribute__((ext_vector_type(8))) short bf16x8;
typedef __attribute__((ext_vector_type(4))) float f32x4;
typedef __attribute__((ext_vector_type(8))) unsigned short ushort8;

typedef void __attribute__((address_space(3)))* lds_ptr_t;
typedef void __attribute__((address_space(1)))* gbl_ptr_t;

__device__ __forceinline__ unsigned short f2bf(float x) {
    return __builtin_bit_cast(unsigned short, __float2bfloat16(x));
}
__device__ __forceinline__ float bf2f(unsigned short u) {
    return __builtin_bit_cast(float, (unsigned)u << 16);
}
__device__ __forceinline__ float tanh_fast(float x) {
    float e = __expf(2.0f * x);
    return 1.0f - 2.0f / (e + 1.0f);
}

// ---------------- fp32 -> bf16 converters ----------------
__global__ __launch_bounds__(256) void k_cvt_bf16(const float* __restrict__ in,
                                                  unsigned short* __restrict__ out, int n4) {
    int i = blockIdx.x * 256 + threadIdx.x;
    if (i < n4) {
        float4 f = reinterpret_cast<const float4*>(in)[i];
        ushort4 u;
        u.x = f2bf(f.x); u.y = f2bf(f.y); u.z = f2bf(f.z); u.w = f2bf(f.w);
        reinterpret_cast<ushort4*>(out)[i] = u;
    }
}

__global__ __launch_bounds__(256) void k_cvt_enc(const float* __restrict__ in,
                                                 unsigned short* __restrict__ out, int n8) {
    const int stride = gridDim.x * 256;
    for (int i = blockIdx.x * 256 + threadIdx.x; i < n8; i += stride) {
        float4 a = reinterpret_cast<const float4*>(in)[(size_t)i * 2];
        float4 b = reinterpret_cast<const float4*>(in)[(size_t)i * 2 + 1];
        ushort8 u;
        u[0] = f2bf(a.x); u[1] = f2bf(a.y); u[2] = f2bf(a.z); u[3] = f2bf(a.w);
        u[4] = f2bf(b.x); u[5] = f2bf(b.y); u[6] = f2bf(b.z); u[7] = f2bf(b.w);
        reinterpret_cast<ushort8*>(out)[i] = u;
    }
}

// ---------------- q_proj[b][o] = sum_k query[b][k] * Ws[o][k] ----------------
__global__ __launch_bounds__(256) void k_qproj(const float* __restrict__ q,
                                               const float* __restrict__ Ws,
                                               float* __restrict__ qp) {
    const int b = blockIdx.y, oc = blockIdx.x, tid = threadIdx.x;
    __shared__ float ql[H_];
    for (int i = tid; i < H_; i += 256) ql[i] = q[b*H_ + i];
    __syncthreads();
    const int o = oc*256 + tid;
    const float4* w = reinterpret_cast<const float4*>(&Ws[(size_t)o * H_]);
    float acc = 0.f;
    #pragma unroll 4
    for (int k4 = 0; k4 < H_/4; ++k4) {
        float4 ww = w[k4];
        acc += ql[k4*4+0]*ww.x + ql[k4*4+1]*ww.y + ql[k4*4+2]*ww.z + ql[k4*4+3]*ww.w;
    }
    qp[b*H_ + o] = acc;
}

// ---------------- fused scores GEMM: r2 structure + fragment-order LDS ----------------
// 128x128 tile, 4 waves, double-buffered LDS, global_load_lds for BOTH operands,
// __syncthreads-per-K-step, ~4 blocks/CU. LDS = 16x32 bf16 subtiles (1024B) stored in
// MFMA FRAGMENT ORDER: byte l*16 = [row l&15][k (l>>4)*8..+7]; staged with the per-lane
// global SOURCE pre-permuted (LDS dest linear base+tid*16) -> conflict-free ds_read_b128.
__global__ __launch_bounds__(256) void k_scores_b(const unsigned short* __restrict__ encb,
                                                  const unsigned short* __restrict__ whb,
                                                  const float* __restrict__ qp,
                                                  const float* __restrict__ vw,
                                                  float* __restrict__ sp) {
    __shared__ __align__(1024) char As[2][8192];   // 8 subtiles x 1024B per buf
    __shared__ __align__(1024) char Bs[2][8192];
    __shared__ float sred[2][128];

    const int tid  = threadIdx.x;
    const int l    = tid & 63;
    const int w    = tid >> 6;       // wave 0..3
    const int wr   = w >> 1;         // row half (rows wr*64..+63)
    const int wc   = w & 1;          // col half
    const int fr   = l & 15;
    const int fh   = l >> 4;

    const int h  = blockIdx.x;                 // 8192 blocks
    const int L  = (h & 7) * 1024 + (h >> 3);  // XCD-group swizzle (bijective)
    const int bm = L >> 3;
    const int bn = L & 7;
    const int row0 = bm * 128;
    const int col0 = bn * 128;
    const int b = row0 >> 12;

    // staging: instr j covers subtiles 4j..4j+3; thread tid -> subtile tid>>6, lane l.
    // source lane-map = fragment order: row (l&15), k-chunk (l>>4)*8.
    const int s_sub = tid >> 6;                // 0..3 within instruction
    const unsigned short* gA0 = encb + (size_t)(row0 + s_sub*16 + fr) * H_ + fh*8;
    const unsigned short* gA1 = gA0 + (size_t)64 * H_;   // subtiles 4..7
    const unsigned short* gB0 = whb  + (size_t)(col0 + s_sub*16 + fr) * H_ + fh*8;
    const unsigned short* gB1 = gB0 + (size_t)64 * H_;

    auto stage = [&](int buf, int kt) {
        char* la = &As[buf][tid*16];
        char* lb = &Bs[buf][tid*16];
        __builtin_amdgcn_global_load_lds((gbl_ptr_t)(gA0 + kt*32), (lds_ptr_t)la,          16, 0, 0);
        __builtin_amdgcn_global_load_lds((gbl_ptr_t)(gA1 + kt*32), (lds_ptr_t)(la + 4096), 16, 0, 0);
        __builtin_amdgcn_global_load_lds((gbl_ptr_t)(gB0 + kt*32), (lds_ptr_t)lb,          16, 0, 0);
        __builtin_amdgcn_global_load_lds((gbl_ptr_t)(gB1 + kt*32), (lds_ptr_t)(lb + 4096), 16, 0, 0);
    };

    f32x4 acc[4][4] = {};

    stage(0, 0);
    __syncthreads();

    for (int kt = 0; kt < 32; ++kt) {
        const int cur = kt & 1, nxt = cur ^ 1;
        if (kt < 31) stage(nxt, kt + 1);

        bf16x8 af[4], bfr[4];
        #pragma unroll
        for (int i = 0; i < 4; ++i) {
            af[i]  = *reinterpret_cast<const bf16x8*>(&As[cur][(wr*4 + i)*1024 + l*16]);
            bfr[i] = *reinterpret_cast<const bf16x8*>(&Bs[cur][(wc*4 + i)*1024 + l*16]);
        }
        #pragma unroll
        for (int i = 0; i < 4; ++i)
            #pragma unroll
            for (int j = 0; j < 4; ++j)
                acc[i][j] = __builtin_amdgcn_mfma_f32_16x16x32_bf16(af[i], bfr[j], acc[i][j], 0, 0, 0);

        __syncthreads();
    }

    // epilogue: s_partial[row] = sum_c v[c] * tanh(qp[b][c] + x[row][c])
    float vv[4], qq[4];
    #pragma unroll
    for (int j = 0; j < 4; ++j) {
        int c = col0 + wc*64 + j*16 + fr;
        vv[j] = vw[c];
        qq[j] = qp[b*H_ + c];
    }
    #pragma unroll
    for (int i = 0; i < 4; ++i) {
        #pragma unroll
        for (int r = 0; r < 4; ++r) {
            float s = 0.f;
            #pragma unroll
            for (int j = 0; j < 4; ++j)
                s += vv[j] * tanh_fast(qq[j] + acc[i][j][r]);
            s += __shfl_xor(s, 1, 64); s += __shfl_xor(s, 2, 64);
            s += __shfl_xor(s, 4, 64); s += __shfl_xor(s, 8, 64);
            if (fr == 0)
                sred[wc][wr*64 + i*16 + fh*4 + r] = s;
        }
    }
    __syncthreads();
    if (tid < 128)
        sp[(size_t)bn * M_ + row0 + tid] = sred[0][tid] + sred[1][tid];
}

// ---------------- fused scores GEMM, fp32 A in-flight (fallback, 128^2) ----------------
__global__ __launch_bounds__(256) void k_scores_f(const float* __restrict__ enc,
                                                  const unsigned short* __restrict__ whb,
                                                  const float* __restrict__ qp,
                                                  const float* __restrict__ vw,
                                                  float* __restrict__ sp) {
    __shared__ __align__(16) unsigned short As[2][128][32];
    __shared__ __align__(16) unsigned short Bs[2][128][32];
    __shared__ float sred[2][128];

    const int tid  = threadIdx.x;
    const int lane = tid & 63;
    const int wid  = tid >> 6;
    const int wr = wid >> 1, wc = wid & 1;
    const int fr = lane & 15;
    const int fk = (lane >> 4) * 8;

    const int h  = blockIdx.x;
    const int L  = (h & 7) * 1024 + (h >> 3);
    const int bm = L >> 3;
    const int bn = L & 7;
    const int row0 = bm * 128;
    const int col0 = bn * 128;
    const int b = row0 >> 12;

    const int ar = tid >> 3;
    const int ak = (tid & 7) * 4;
    const int bnr = tid >> 2;
    const int bkk = (tid & 3) * 8;

    float4 areg[4];
    auto loadA = [&](int kt) {
        #pragma unroll
        for (int p = 0; p < 4; ++p)
            areg[p] = *reinterpret_cast<const float4*>(
                &enc[(size_t)(row0 + p*32 + ar) * H_ + kt*32 + ak]);
    };
    auto writeA = [&](int buf) {
        #pragma unroll
        for (int p = 0; p < 4; ++p) {
            ushort4 u;
            u.x = f2bf(areg[p].x); u.y = f2bf(areg[p].y);
            u.z = f2bf(areg[p].z); u.w = f2bf(areg[p].w);
            *reinterpret_cast<ushort4*>(&As[buf][p*32 + ar][ak]) = u;
        }
    };
    auto stageB = [&](int buf, int kt) {
        const unsigned short* g0 = whb + (size_t)(col0 + bnr) * H_ + kt*32 + bkk;
        const unsigned short* g1 = g0 + (size_t)64 * H_;
        char* l0 = (char*)(&Bs[buf][0][0]) + tid*16;
        __builtin_amdgcn_global_load_lds((gbl_ptr_t)g0, (lds_ptr_t)l0,        16, 0, 0);
        __builtin_amdgcn_global_load_lds((gbl_ptr_t)g1, (lds_ptr_t)(l0+4096), 16, 0, 0);
    };

    f32x4 acc[4][4] = {};

    loadA(0);
    stageB(0, 0);
    writeA(0);
    __syncthreads();

    for (int kt = 0; kt < 32; ++kt) {
        const int cur = kt & 1, nxt = cur ^ 1;
        if (kt < 31) { stageB(nxt, kt + 1); loadA(kt + 1); }

        bf16x8 af[4], bfr[4];
        #pragma unroll
        for (int i = 0; i < 4; ++i) {
            af[i]  = *reinterpret_cast<const bf16x8*>(&As[cur][wr*64 + i*16 + fr][fk]);
            bfr[i] = *reinterpret_cast<const bf16x8*>(&Bs[cur][wc*64 + i*16 + fr][fk]);
        }
        #pragma unroll
        for (int i = 0; i < 4; ++i)
            #pragma unroll
            for (int j = 0; j < 4; ++j)
                acc[i][j] = __builtin_amdgcn_mfma_f32_16x16x32_bf16(af[i], bfr[j], acc[i][j], 0, 0, 0);

        if (kt < 31) writeA(nxt);
        __syncthreads();
    }

    float vv[4], qq[4];
    #pragma unroll
    for (int j = 0; j < 4; ++j) {
        int c = col0 + wc*64 + j*16 + fr;
        vv[j] = vw[c];
        qq[j] = qp[b*H_ + c];
    }
    #pragma unroll
    for (int i = 0; i < 4; ++i) {
        #pragma unroll
        for (int r = 0; r < 4; ++r) {
            float s = 0.f;
            #pragma unroll
            for (int j = 0; j < 4; ++j)
                s += vv[j] * tanh_fast(qq[j] + acc[i][j][r]);
            #pragma unroll
            for (int m = 1; m < 16; m <<= 1)
                s += __shfl_xor(s, m, 64);
            if (fr == 0)
                sred[wc][wr*64 + i*16 + (lane >> 4)*4 + r] = s;
        }
    }
    __syncthreads();
    if (tid < 128)
        sp[(size_t)bn * M_ + row0 + tid] = sred[0][tid] + sred[1][tid];
}

// ---------------- softmax over S per batch (P partial panels) ----------------
__global__ __launch_bounds__(256) void k_softmax(const float* __restrict__ sp,
                                                 float* __restrict__ attn, int P) {
    const int b = blockIdx.x, tid = threadIdx.x;
    __shared__ float red[4];
    float vals[16];
    float mx = -1e30f;
    #pragma unroll
    for (int i = 0; i < 16; ++i) {
        int s = i*256 + tid;
        float x = 0.f;
        for (int p = 0; p < P; ++p) x += sp[(size_t)p*M_ + b*S_ + s];
        vals[i] = x;
        mx = fmaxf(mx, x);
    }
    #pragma unroll
    for (int m = 1; m < 64; m <<= 1) mx = fmaxf(mx, __shfl_xor(mx, m, 64));
    if ((tid & 63) == 0) red[tid >> 6] = mx;
    __syncthreads();
    mx = fmaxf(fmaxf(red[0], red[1]), fmaxf(red[2], red[3]));
    float sum = 0.f;
    #pragma unroll
    for (int i = 0; i < 16; ++i) { vals[i] = __expf(vals[i] - mx); sum += vals[i]; }
    #pragma unroll
    for (int m = 1; m < 64; m <<= 1) sum += __shfl_xor(sum, m, 64);
    __syncthreads();
    if ((tid & 63) == 0) red[tid >> 6] = sum;
    __syncthreads();
    sum = red[0] + red[1] + red[2] + red[3];
    float inv = 1.f / sum;
    #pragma unroll
    for (int i = 0; i < 16; ++i) attn[b*S_ + i*256 + tid] = vals[i] * inv;
}

// ---------------- ctx partials, bf16 enc ----------------
__global__ __launch_bounds__(256) void k_ctx_b(const float* __restrict__ attn,
                                               const unsigned short* __restrict__ encb,
                                               float* __restrict__ ctxp) {
    const int sc = blockIdx.x;      // 0..15
    const int b  = blockIdx.y;
    const int hh = threadIdx.x * 4;
    float ax = 0.f, ay = 0.f, az = 0.f, aw = 0.f;
    const int s0 = sc * 256;
    #pragma unroll 4
    for (int s = s0; s < s0 + 256; ++s) {
        float a = attn[b*S_ + s];
        ushort4 e = *reinterpret_cast<const ushort4*>(&encb[((size_t)b*S_ + s) * H_ + hh]);
        ax += a*bf2f(e.x); ay += a*bf2f(e.y); az += a*bf2f(e.z); aw += a*bf2f(e.w);
    }
    float4 o; o.x = ax; o.y = ay; o.z = az; o.w = aw;
    *reinterpret_cast<float4*>(&ctxp[((size_t)sc*B_ + b) * H_ + hh]) = o;
}

// ---------------- ctx partials, fp32 enc (fallback) ----------------
__global__ __launch_bounds__(256) void k_ctx_f(const float* __restrict__ attn,
                                               const float* __restrict__ enc,
                                               float* __restrict__ ctxp) {
    const int sc = blockIdx.x;
    const int b  = blockIdx.y;
    const int hh = threadIdx.x * 4;
    float ax = 0.f, ay = 0.f, az = 0.f, aw = 0.f;
    const int s0 = sc * 256;
    #pragma unroll 4
    for (int s = s0; s < s0 + 256; ++s) {
        float a = attn[b*S_ + s];
        float4 e = *reinterpret_cast<const float4*>(&enc[((size_t)b*S_ + s) * H_ + hh]);
        ax += a*e.x; ay += a*e.y; az += a*e.z; aw += a*e.w;
    }
    float4 o; o.x = ax; o.y = ay; o.z = az; o.w = aw;
    *reinterpret_cast<float4*>(&ctxp[((size_t)sc*B_ + b) * H_ + hh]) = o;
}

// ---------------- out[b][o] = tanh(sum_k cat[b][k] * Wout[o][k]) ----------------
__global__ __launch_bounds__(256) void k_out(const float* __restrict__ ctxp,
                                             const float* __restrict__ q,
                                             const float* __restrict__ Wout,
                                             float* __restrict__ out) {
    const int oc = blockIdx.x, b = blockIdx.y, tid = threadIdx.x;
    __shared__ float cat[2*H_];
    for (int k = tid; k < H_; k += 256) {
        float s = 0.f;
        #pragma unroll
        for (int p = 0; p < 16; ++p) s += ctxp[((size_t)p*B_ + b) * H_ + k];
        cat[k] = s;
        cat[H_ + k] = q[b*H_ + k];
    }
    __syncthreads();
    const int o = oc*256 + tid;
    const float4* w = reinterpret_cast<const float4*>(&Wout[(size_t)o * 2*H_]);
    float acc = 0.f;
    #pragma unroll 4
    for (int k4 = 0; k4 < 2*H_/4; ++k4) {
        float4 ww = w[k4];
        acc += cat[k4*4+0]*ww.x + cat[k4*4+1]*ww.y + cat[k4*4+2]*ww.z + cat[k4*4+3]*ww.w;
    }
    out[b*H_ + o] = tanh_fast(acc);
}

extern "C" void kernel_launch(void* const* d_in, const int* in_sizes, int n_in,
                              void* d_out, int out_size, void* d_ws, size_t ws_size,
                              hipStream_t stream) {
    const float* query = (const float*)d_in[0];
    const float* enc   = (const float*)d_in[1];
    // d_in[2] = src_lengths (int64) — dead in the reference, faithfully unused
    const float* Ws    = (const float*)d_in[3];
    const float* Wh    = (const float*)d_in[4];
    const float* vw    = (const float*)d_in[5];
    const float* Wout  = (const float*)d_in[6];
    float* out = (float*)d_out;

    char* ws = (char*)d_ws;

    if (ws_size >= (266ull << 20)) {
        unsigned short* encb = (unsigned short*)ws;                        // 256 MiB
        unsigned short* whb  = (unsigned short*)(ws + (256ull << 20));     // 2 MiB
        float* sp   = (float*)(ws + (258ull << 20));                       // [8][M] 4 MiB
        float* attn = (float*)(ws + (262ull << 20));                       // 512 KiB
        float* qp   = (float*)(ws + (262ull << 20) + (512u << 10));        // 128 KiB
        float* ctxp = (float*)(ws + (263ull << 20));                       // 2 MiB

        k_cvt_enc <<<dim3(2048),    dim3(256), 0, stream>>>(enc, encb, M_*H_/8);
        k_cvt_bf16<<<dim3(1024),    dim3(256), 0, stream>>>(Wh, whb, H_*H_/4);
        k_qproj   <<<dim3(4, 32),   dim3(256), 0, stream>>>(query, Ws, qp);
        k_scores_b<<<dim3(8192),    dim3(256), 0, stream>>>(encb, whb, qp, vw, sp);
        k_softmax <<<dim3(32),      dim3(256), 0, stream>>>(sp, attn, 8);
        k_ctx_b   <<<dim3(16, 32),  dim3(256), 0, stream>>>(attn, encb, ctxp);
        k_out     <<<dim3(4, 32),   dim3(256), 0, stream>>>(ctxp, query, Wout, out);
    } else {
        unsigned short* whb = (unsigned short*)ws;
        float* sp   = (float*)(ws + (2u  << 20));
        float* attn = (float*)(ws + (6u  << 20));
        float* qp   = (float*)(ws + (6u  << 20) + (512u << 10));
        float* ctxp = (float*)(ws + (7u  << 20));

        k_cvt_bf16<<<dim3(1024),    dim3(256), 0, stream>>>(Wh, whb, H_*H_/4);
        k_qproj   <<<dim3(4, 32),   dim3(256), 0, stream>>>(query, Ws, qp);
        k_scores_f<<<dim3(8192),    dim3(256), 0, stream>>>(enc, whb, qp, vw, sp);
        k_softmax <<<dim3(32),      dim3(256), 0, stream>>>(sp, attn, 8);
        k_ctx_f   <<<dim3(16, 32),  dim3(256), 0, stream>>>(attn, enc, ctxp);
        k_out     <<<dim3(4, 32),   dim3(256), 0, stream>>>(ctxp, query, Wout, out);
    }
}